// Round 16
// baseline (24075.188 us; speedup 1.0000x reference)
//
#include <hip/hip_runtime.h>
#include <math.h>

// ---------------------------------------------------------------------------
// NeuralMemory (Titans-style). Round 13..16: persistent fence-free scan,
// REGISTER-resident state, 128 WGs.
// History: r8 threadfence barriers 45us/bar; r9 kernel-boundary 10.5us/disp
// (23.1ms); r11 scalar-atomic data path unstable (~30us/step); r12 LDS-staged
// 8B agent loads -> 11.2us/step, 12.57ms total, stable. r13: all W/S state is
// wave-private -> move from LDS to registers (72 VGPR/lane); LDS holds only
// the 24KB exchange tile; cut barrier participants 256->128 WGs (384 thr,
// 6 waves, 1 row/wave). Barrier logic unchanged (master/broadcast, relaxed
// agent atomics, no fences).
// B=8, S=1024, D=768, GH=32, THETA=0.01
// ---------------------------------------------------------------------------

#define S_LEN 1024
#define D_DIM 768
#define B_SZ 8
#define NWG 128      // scan workgroups
#define NTHR 384     // 6 waves; wave w owns row jg = wg*6 + w
#define THETA_F 0.01f
#define FLAG_STRIDE 16   // one 64B cacheline per arrival flag

__device__ __forceinline__ void st_agent(float* p, float v) {
  __hip_atomic_store(p, v, __ATOMIC_RELAXED, __HIP_MEMORY_SCOPE_AGENT);
}

__device__ __forceinline__ void load12(const float* __restrict__ p, float* d) {
  float4 a = ((const float4*)p)[0], b = ((const float4*)p)[1],
         c = ((const float4*)p)[2];
  d[0]=a.x; d[1]=a.y; d[2]=a.z; d[3]=a.w;
  d[4]=b.x; d[5]=b.y; d[6]=b.z; d[7]=b.w;
  d[8]=c.x; d[9]=c.y; d[10]=c.z; d[11]=c.w;
}
__device__ __forceinline__ void store12(float* __restrict__ p, const float* s) {
  ((float4*)p)[0] = make_float4(s[0], s[1], s[2], s[3]);
  ((float4*)p)[1] = make_float4(s[4], s[5], s[6], s[7]);
  ((float4*)p)[2] = make_float4(s[8], s[9], s[10], s[11]);
}

// ---------------------------------------------------------------------------
// Generic f32 GEMM (unchanged since round 2; validated)
// ---------------------------------------------------------------------------
template <int ACT, int REMAP>
__global__ __launch_bounds__(256) void gemm_tn(const float* __restrict__ A,
                                               const float* __restrict__ W,
                                               const float* __restrict__ bias,
                                               float* __restrict__ C) {
  __shared__ float As[16][132];
  __shared__ float Ws[16][68];
  const int tid = threadIdx.x;
  const int txx = tid & 15, tyy = tid >> 4;
  const int eb = blockIdx.x * 64;
  const int nb = blockIdx.y * 128;
  float acc[8][4];
#pragma unroll
  for (int i = 0; i < 8; ++i)
#pragma unroll
    for (int j = 0; j < 4; ++j) acc[i][j] = 0.f;

  const int lr = tid >> 2;          // 0..63
  const int lc = (tid & 3) << 2;    // 0,4,8,12

  for (int k0 = 0; k0 < 768; k0 += 16) {
    float4 a0 = *(const float4*)(A + (size_t)(nb + lr) * 768 + k0 + lc);
    float4 a1 = *(const float4*)(A + (size_t)(nb + lr + 64) * 768 + k0 + lc);
    float4 wv = *(const float4*)(W + (size_t)(eb + lr) * 768 + k0 + lc);
    __syncthreads();
    As[lc + 0][lr] = a0.x; As[lc + 1][lr] = a0.y; As[lc + 2][lr] = a0.z; As[lc + 3][lr] = a0.w;
    As[lc + 0][lr + 64] = a1.x; As[lc + 1][lr + 64] = a1.y; As[lc + 2][lr + 64] = a1.z; As[lc + 3][lr + 64] = a1.w;
    Ws[lc + 0][lr] = wv.x; Ws[lc + 1][lr] = wv.y; Ws[lc + 2][lr] = wv.z; Ws[lc + 3][lr] = wv.w;
    __syncthreads();
#pragma unroll
    for (int kk = 0; kk < 16; ++kk) {
      float4 x0 = *(const float4*)(&As[kk][tyy * 8]);
      float4 x1 = *(const float4*)(&As[kk][tyy * 8 + 4]);
      float4 y0 = *(const float4*)(&Ws[kk][txx * 4]);
      float a8[8] = {x0.x, x0.y, x0.z, x0.w, x1.x, x1.y, x1.z, x1.w};
      float b4[4] = {y0.x, y0.y, y0.z, y0.w};
#pragma unroll
      for (int i = 0; i < 8; ++i)
#pragma unroll
        for (int j = 0; j < 4; ++j) acc[i][j] = fmaf(a8[i], b4[j], acc[i][j]);
    }
  }
  float4 bv = *(const float4*)(bias + eb + txx * 4);
#pragma unroll
  for (int i = 0; i < 8; ++i) {
    int n = nb + tyy * 8 + i;
    float4 o;
    o.x = acc[i][0] + bv.x; o.y = acc[i][1] + bv.y;
    o.z = acc[i][2] + bv.z; o.w = acc[i][3] + bv.w;
    if (ACT == 1) {
      o.x = o.x / (1.f + expf(-o.x));
      o.y = o.y / (1.f + expf(-o.y));
      o.z = o.z / (1.f + expf(-o.z));
      o.w = o.w / (1.f + expf(-o.w));
    }
    size_t row = REMAP ? (size_t)((n & 1023) * 8 + (n >> 10)) : (size_t)n;
    *(float4*)(C + row * 768 + eb + txx * 4) = o;
  }
}

// ---------------------------------------------------------------------------
// Gate scalars (unchanged; validated)
// ---------------------------------------------------------------------------
__global__ __launch_bounds__(512) void gates_kernel(
    const float* __restrict__ x, const float* __restrict__ FGW1,
    const float* __restrict__ FGb1, const float* __restrict__ FGw2,
    const float* __restrict__ FGb2, const float* __restrict__ DGW1,
    const float* __restrict__ DGb1, const float* __restrict__ DGw2,
    const float* __restrict__ DGb2, float* __restrict__ alphaA,
    float* __restrict__ etaA) {
  __shared__ float sA[8], sE[8];
  const int t = blockIdx.x, tid = threadIdx.x;
  const int b = tid >> 6, lane = tid & 63;
  const bool isFG = lane < 32;
  const int h = lane & 31;
  const float* xr = x + ((size_t)b * S_LEN + t) * D_DIM;
  const float* Wr = (isFG ? FGW1 : DGW1) + (size_t)h * D_DIM;
  float acc = 0.f;
  for (int d = 0; d < D_DIM; d += 4) {
    float4 xv = *(const float4*)(xr + d);
    float4 wv = *(const float4*)(Wr + d);
    acc = fmaf(xv.x, wv.x, acc);
    acc = fmaf(xv.y, wv.y, acc);
    acc = fmaf(xv.z, wv.z, acc);
    acc = fmaf(xv.w, wv.w, acc);
  }
  float z = acc + (isFG ? FGb1[h] : DGb1[h]);
  float sg = 1.f / (1.f + expf(-z));
  float p = z * sg * (isFG ? FGw2[h] : DGw2[h]);
#pragma unroll
  for (int off = 16; off > 0; off >>= 1) p += __shfl_xor(p, off, 64);
  if (lane == 0) sA[b] = 1.f / (1.f + expf(-(p + FGb2[0])));
  if (lane == 32) sE[b] = 1.f / (1.f + expf(-(p + DGb2[0])));
  __syncthreads();
  if (tid == 0) {
    float sa = 0.f, se = 0.f;
#pragma unroll
    for (int i = 0; i < 8; ++i) { sa += sA[i]; se += sE[i]; }
    alphaA[t] = sa * 0.125f;
    etaA[t] = se * 0.125f;
  }
}

// ---------------------------------------------------------------------------
// Master/broadcast grid barrier (same protocol as r11/r12; NWG=128 now).
// ---------------------------------------------------------------------------
__device__ __forceinline__ void grid_barrier(int* arrive, int* go, int wg,
                                             int tid, int epoch) {
  __syncthreads();
  if (wg == 0) {
#pragma unroll 1
    for (int s = tid + 1; s < NWG; s += NTHR) {
      while (__hip_atomic_load(arrive + s * FLAG_STRIDE, __ATOMIC_RELAXED,
                               __HIP_MEMORY_SCOPE_AGENT) < epoch) {
        __builtin_amdgcn_s_sleep(1);
      }
    }
    __syncthreads();
    if (tid == 0)
      __hip_atomic_store(go, epoch, __ATOMIC_RELAXED,
                         __HIP_MEMORY_SCOPE_AGENT);
  } else {
    if (tid == 0) {
      __hip_atomic_store(arrive + wg * FLAG_STRIDE, epoch, __ATOMIC_RELAXED,
                         __HIP_MEMORY_SCOPE_AGENT);
      while (__hip_atomic_load(go, __ATOMIC_RELAXED,
                               __HIP_MEMORY_SCOPE_AGENT) < epoch) {
        __builtin_amdgcn_s_sleep(1);
      }
    }
    __syncthreads();
  }
}

// ---------------------------------------------------------------------------
// Stage the 6144-float exchange tile into LDS: 384 thr x 8 independent 8B
// relaxed-agent loads (LLC-coherent), then 8B LDS writes.
// ---------------------------------------------------------------------------
__device__ __forceinline__ void stage_tile(const float* gsrc, float* sdst,
                                           int tid) {
  const unsigned long long* src = (const unsigned long long*)gsrc;
  unsigned long long u[8];
#pragma unroll
  for (int j = 0; j < 8; ++j)
    u[j] = __hip_atomic_load(src + tid + j * NTHR, __ATOMIC_RELAXED,
                             __HIP_MEMORY_SCOPE_AGENT);
  unsigned long long* dst = (unsigned long long*)sdst;
#pragma unroll
  for (int j = 0; j < 8; ++j) dst[tid + j * NTHR] = u[j];
}

// ---------------------------------------------------------------------------
// Persistent scan. 128 WGs x 384 thr; wave w owns row jg = wg*6+w of all six
// state matrices, held in REGISTERS (12 floats per lane per matrix). Biases
// are wave-uniform registers (reduced values are lane-identical). LDS holds
// only the 24KB h1/dOut exchange tile. 2 fence-free grid barriers per step.
// ---------------------------------------------------------------------------
__global__ __launch_bounds__(NTHR, 1) void scan_kernel(
    const float* __restrict__ kbuf, const float* __restrict__ vbuf,
    const float* __restrict__ alphaA, const float* __restrict__ etaA,
    const float* __restrict__ MW1, const float* __restrict__ Mb1,
    const float* __restrict__ MW2, const float* __restrict__ Mb2,
    float* __restrict__ W1f, float* __restrict__ b1f, float* __restrict__ W2f,
    float* __restrict__ b2f, float* h1g, float* dOg,
    int* arrive, int* go) {
  __shared__ float sTile[6144];

  const int tid = threadIdx.x, wg = blockIdx.x;
  const int w = tid >> 6, lane = tid & 63;
  const int jg = wg * 6 + w;
  const int colb = lane * 12;

  // ---- state in registers ----
  float w1[12], s1[12], w2[12], s2[12], w2t[12], s2t[12];
  load12(MW1 + (size_t)jg * 768 + colb, w1);
  load12(MW2 + (size_t)jg * 768 + colb, w2);
#pragma unroll
  for (int m = 0; m < 12; ++m) {
    w2t[m] = MW2[(size_t)(colb + m) * 768 + jg];
    s1[m] = 0.f; s2[m] = 0.f; s2t[m] = 0.f;
  }
  float b1v = Mb1[jg], b2v = Mb2[jg], sb1v = 0.f, sb2v = 0.f;

  int epoch = 0;
  float hprev[8], sgv[8], h1loc[8];
  const float c0 = 2.0f / 6144.0f;

  for (int t = 0; t < S_LEN; ++t) {
    const float a_t = alphaA[t], e_t = etaA[t];
    const float om_a = 1.0f - a_t;

    // ---- phase A: h1[b,jg] = silu(k_t[b,:] . w1 + b1) ----
    {
      float acc[8];
#pragma unroll
      for (int b = 0; b < 8; ++b) {
        float kv[12];
        load12(kbuf + ((size_t)t * 8 + b) * 768 + colb, kv);
        float a = 0.f;
#pragma unroll
        for (int m = 0; m < 12; ++m) a = fmaf(kv[m], w1[m], a);
        acc[b] = a;
      }
#pragma unroll
      for (int off = 32; off > 0; off >>= 1)
#pragma unroll
        for (int b = 0; b < 8; ++b) acc[b] += __shfl_xor(acc[b], off, 64);
#pragma unroll
      for (int b = 0; b < 8; ++b) {
        float z = acc[b] + b1v;
        float sg = 1.0f / (1.0f + expf(-z));
        hprev[b] = z; sgv[b] = sg; h1loc[b] = z * sg;
      }
#pragma unroll
      for (int b = 0; b < 8; ++b)
        if (lane == b) st_agent(h1g + b * 768 + jg, h1loc[b]);
    }
    grid_barrier(arrive, go, wg, tid, ++epoch);

    // ---- phase B: out, dOut; update W2,b2 ----
    {
      stage_tile(h1g, sTile, tid);
      __syncthreads();
      float acc[8];
#pragma unroll
      for (int b = 0; b < 8; ++b) {
        float hv[12];
        load12(&sTile[b * 768 + colb], hv);
        float a = 0.f;
#pragma unroll
        for (int m = 0; m < 12; ++m) a = fmaf(hv[m], w2[m], a);
        acc[b] = a;
      }
#pragma unroll
      for (int off = 32; off > 0; off >>= 1)
#pragma unroll
        for (int b = 0; b < 8; ++b) acc[b] += __shfl_xor(acc[b], off, 64);
      float dOv[8];
#pragma unroll
      for (int b = 0; b < 8; ++b) {
        float outv = acc[b] + b2v;
        dOv[b] = c0 * (outv - vbuf[((size_t)t * 8 + b) * 768 + jg]);
        if (lane == b) st_agent(dOg + b * 768 + jg, dOv[b]);
      }
      float gm[12];
#pragma unroll
      for (int m = 0; m < 12; ++m) gm[m] = 0.f;
#pragma unroll
      for (int b = 0; b < 8; ++b) {
        float hv[12];
        load12(&sTile[b * 768 + colb], hv);
#pragma unroll
        for (int m = 0; m < 12; ++m) gm[m] = fmaf(dOv[b], hv[m], gm[m]);
      }
#pragma unroll
      for (int m = 0; m < 12; ++m) {
        s2[m] = e_t * s2[m] - THETA_F * gm[m];
        w2[m] = om_a * w2[m] + s2[m];
      }
      float gb = dOv[0] + dOv[1] + dOv[2] + dOv[3] + dOv[4] + dOv[5] +
                 dOv[6] + dOv[7];
      sb2v = e_t * sb2v - THETA_F * gb;
      b2v = om_a * b2v + sb2v;
    }
    grid_barrier(arrive, go, wg, tid, ++epoch);

    // ---- phase C: dh1 -> dpre; update W1,b1,W2T ----
    {
      stage_tile(dOg, sTile, tid);
      __syncthreads();
      float acc[8];
#pragma unroll
      for (int b = 0; b < 8; ++b) {
        float dv[12];
        load12(&sTile[b * 768 + colb], dv);
        float a = 0.f;
#pragma unroll
        for (int m = 0; m < 12; ++m) a = fmaf(dv[m], w2t[m], a);
        acc[b] = a;
      }
#pragma unroll
      for (int off = 32; off > 0; off >>= 1)
#pragma unroll
        for (int b = 0; b < 8; ++b) acc[b] += __shfl_xor(acc[b], off, 64);
      float dpre[8];
#pragma unroll
      for (int b = 0; b < 8; ++b)
        dpre[b] = acc[b] * (sgv[b] * (1.0f + hprev[b] * (1.0f - sgv[b])));
      // W1 update (grad = dpre x k_t)
      float gm[12];
#pragma unroll
      for (int m = 0; m < 12; ++m) gm[m] = 0.f;
#pragma unroll
      for (int b = 0; b < 8; ++b) {
        float kv[12];
        load12(kbuf + ((size_t)t * 8 + b) * 768 + colb, kv);
#pragma unroll
        for (int m = 0; m < 12; ++m) gm[m] = fmaf(dpre[b], kv[m], gm[m]);
      }
#pragma unroll
      for (int m = 0; m < 12; ++m) {
        s1[m] = e_t * s1[m] - THETA_F * gm[m];
        w1[m] = om_a * w1[m] + s1[m];
      }
      // W2T update (grad = h1 x dOut)
#pragma unroll
      for (int m = 0; m < 12; ++m) gm[m] = 0.f;
#pragma unroll
      for (int b = 0; b < 8; ++b) {
        float dv[12];
        load12(&sTile[b * 768 + colb], dv);
#pragma unroll
        for (int m = 0; m < 12; ++m) gm[m] = fmaf(h1loc[b], dv[m], gm[m]);
      }
#pragma unroll
      for (int m = 0; m < 12; ++m) {
        s2t[m] = e_t * s2t[m] - THETA_F * gm[m];
        w2t[m] = om_a * w2t[m] + s2t[m];
      }
      float gb = dpre[0] + dpre[1] + dpre[2] + dpre[3] + dpre[4] + dpre[5] +
                 dpre[6] + dpre[7];
      sb1v = e_t * sb1v - THETA_F * gb;
      b1v = om_a * b1v + sb1v;
    }
    // no barrier before next A: C's sTile reads are protected by barrier1(t+1)
    // (dOg rewritten only after it); h1g rewritten in A(t+1) only after
    // barrier2(t), by which time B(t)'s staging reads are done.
  }

  // ---- dump final params ----
  store12(W1f + (size_t)jg * 768 + colb, w1);
  store12(W2f + (size_t)jg * 768 + colb, w2);
  if (lane == 0) {
    b1f[jg] = b1v;
    b2f[jg] = b2v;
  }
}

// ---------------------------------------------------------------------------
extern "C" void kernel_launch(void* const* d_in, const int* in_sizes, int n_in,
                              void* d_out, int out_size, void* d_ws,
                              size_t ws_size, hipStream_t stream) {
  (void)in_sizes; (void)n_in; (void)out_size; (void)ws_size;
  const float* x   = (const float*)d_in[0];
  const float* WKw = (const float*)d_in[1];
  const float* WKb = (const float*)d_in[2];
  const float* WVw = (const float*)d_in[3];
  const float* WVb = (const float*)d_in[4];
  const float* WQw = (const float*)d_in[5];
  const float* WQb = (const float*)d_in[6];
  const float* MW1 = (const float*)d_in[7];
  const float* Mb1 = (const float*)d_in[8];
  const float* MW2 = (const float*)d_in[9];
  const float* Mb2 = (const float*)d_in[10];
  const float* FGW1 = (const float*)d_in[11];
  const float* FGb1 = (const float*)d_in[12];
  const float* FGw2 = (const float*)d_in[13];
  const float* FGb2 = (const float*)d_in[14];
  const float* DGW1 = (const float*)d_in[15];
  const float* DGb1 = (const float*)d_in[16];
  const float* DGw2 = (const float*)d_in[17];
  const float* DGb2 = (const float*)d_in[18];
  float* out = (float*)d_out;

  // workspace layout (floats); q/h1q alias k/v after the scan.
  float* ws = (float*)d_ws;
  float* kbuf = ws;                       // [S,B,D]
  float* vbuf = ws + 6291456;             // [S,B,D]
  float* W1f  = ws + 12582912;            // [768,768]
  float* W2f  = W1f + 589824;
  float* b1f  = W2f + 589824;             // [768]
  float* b2f  = b1f + 768;
  float* alphaA = b2f + 768;              // [1024]
  float* etaA   = alphaA + 1024;
  float* h1g  = etaA + 1024;              // [8,768]
  float* dOg  = h1g + 6144;               // [8,768]
  int* arrive = (int*)(dOg + 6144);       // [NWG*FLAG_STRIDE]
  int* go     = arrive + NWG * FLAG_STRIDE;
  float* qbuf = kbuf;
  float* h1q  = vbuf;

  hipMemsetAsync(arrive, 0, (NWG * FLAG_STRIDE + FLAG_STRIDE) * sizeof(int),
                 stream);

  dim3 gg(12, 64), bb(256);
  gemm_tn<0, 1><<<gg, bb, 0, stream>>>(x, WKw, WKb, kbuf);
  gemm_tn<0, 1><<<gg, bb, 0, stream>>>(x, WVw, WVb, vbuf);
  gates_kernel<<<dim3(1024), dim3(512), 0, stream>>>(
      x, FGW1, FGb1, FGw2, FGb2, DGW1, DGb1, DGw2, DGb2, alphaA, etaA);
  scan_kernel<<<dim3(NWG), dim3(NTHR), 0, stream>>>(
      kbuf, vbuf, alphaA, etaA, MW1, Mb1, MW2, Mb2, W1f, b1f, W2f, b2f, h1g,
      dOg, arrive, go);
  gemm_tn<0, 0><<<gg, bb, 0, stream>>>(x, WQw, WQb, qbuf);
  gemm_tn<1, 0><<<gg, bb, 0, stream>>>(qbuf, W1f, b1f, h1q);
  gemm_tn<0, 0><<<gg, bb, 0, stream>>>(h1q, W2f, b2f, out);
}